// Round 1
// baseline (472.347 us; speedup 1.0000x reference)
//
#include <hip/hip_runtime.h>

// ---------------------------------------------------------------------------
// VARS_D: fused linear-attention block on gfx950. Round 5.
//  - qkv + proj GEMMs rebuilt as 256x256-tile, 8-wave, double-buffered
//    counted-vmcnt schedule (T3+T4) with setprio (T5), XOR k-chunk swizzle
//    (T2), XCD-grouped grid (T1). Never drains vmcnt to 0 in steady state.
//  - everything else unchanged from round 4.
// ---------------------------------------------------------------------------

typedef __attribute__((ext_vector_type(8))) short bf16x8;
typedef __attribute__((ext_vector_type(4))) float f32x4;

#define GLD16(gptr, lptr)                                                              \
  __builtin_amdgcn_global_load_lds((const __attribute__((address_space(1))) void*)(gptr), \
                                   (__attribute__((address_space(3))) void*)(lptr), 16, 0, 0)

__device__ __forceinline__ unsigned short f2bf(float f) {
  union { float f; unsigned int u; } v; v.f = f;
  unsigned int r = v.u + 0x7fffu + ((v.u >> 16) & 1u);   // RNE
  return (unsigned short)(r >> 16);
}
__device__ __forceinline__ float bf2f(unsigned short s) {
  union { unsigned int u; float f; } v; v.u = ((unsigned int)s) << 16;
  return v.f;
}
__device__ __forceinline__ float rn_of(float css) {
  return 1.f / fmaxf(sqrtf(css), 1e-12f);
}

// ---------------------------------------------------------------------------
// 256x256 NT GEMM core, BK=32, 8 waves (2M x 4N), LDS double-buffer,
// counted vmcnt(4) pipeline, setprio around MFMA clusters.
// A[256 rows, ldk], B[256 rows, ldk], both bf16 row-major (NT).
// LDS layout per buffer: A 8192 shorts, B 8192 shorts; rows of 4 x 16B
// chunks, chunk position XOR-swizzled by ((row>>1)&3) (write side folds the
// swizzle into the global source address; global_load_lds dest stays linear).
// ---------------------------------------------------------------------------
template<int KT>
__device__ __forceinline__ void gemm256_core(
    const unsigned short* __restrict__ A,
    const unsigned short* __restrict__ B,
    int ldk,
    f32x4 (&acc)[8][4],
    unsigned short* smem) {
  const int tid = threadIdx.x;
  const int lane = tid & 63, wave = tid >> 6;
  const int l16 = lane & 15, quad = lane >> 4;
  const int wr = wave >> 2, wc = wave & 3;
  const int fsw = (l16 >> 1) & 3;
  const int r0 = tid >> 2;
  const int gsw = (((tid & 3) ^ ((r0 >> 1) & 3)) << 3);  // swizzled k-offset (elems)

#pragma unroll
  for (int i = 0; i < 8; i++)
#pragma unroll
    for (int j = 0; j < 4; j++)
#pragma unroll
      for (int r = 0; r < 4; r++) acc[i][j][r] = 0.f;

  const unsigned short* Ag0 = A + (long)r0 * ldk + gsw;
  const unsigned short* Ag1 = A + (long)(r0 + 128) * ldk + gsw;
  const unsigned short* Bg0 = B + (long)r0 * ldk + gsw;
  const unsigned short* Bg1 = B + (long)(r0 + 128) * ldk + gsw;
  const int ldsW = wave * 64 * 8;  // wave-uniform lds chunk base (shorts)

  auto stage = [&](int t, int b) {
    unsigned short* Ab = smem + b * 16384;
    unsigned short* Bb = Ab + 8192;
    const int k0 = t * 32;
    GLD16(Ag0 + k0, Ab + ldsW);
    GLD16(Ag1 + k0, Ab + 4096 + ldsW);
    GLD16(Bg0 + k0, Bb + ldsW);
    GLD16(Bg1 + k0, Bb + 4096 + ldsW);
  };

  // prologue: tiles 0,1 in flight; wait for tile 0 only (counted).
  stage(0, 0);
  stage(1, 1);
  asm volatile("s_waitcnt vmcnt(4)" ::: "memory");
  __builtin_amdgcn_s_barrier();

  for (int t = 0; t < KT; t++) {
    const int b = t & 1;
    const unsigned short* Ab = smem + b * 16384;
    const unsigned short* Bb = Ab + 8192;
    // ---- phase 1: all frag ds_reads, drained BEFORE barrier so phase-2
    //      staging into this buffer can never land on unread data.
    bf16x8 af[8], bf[4];
#pragma unroll
    for (int i = 0; i < 8; i++)
      af[i] = *(const bf16x8*)(Ab + (wr * 128 + i * 16 + l16) * 32 + ((quad ^ fsw) * 8));
#pragma unroll
    for (int j = 0; j < 4; j++)
      bf[j] = *(const bf16x8*)(Bb + (wc * 64 + j * 16 + l16) * 32 + ((quad ^ fsw) * 8));
    asm volatile("s_waitcnt lgkmcnt(0)" ::: "memory");
    __builtin_amdgcn_s_barrier();
    __builtin_amdgcn_s_setprio(1);
#pragma unroll
    for (int i = 0; i < 8; i++)
#pragma unroll
      for (int j = 0; j < 2; j++)
        acc[i][j] = __builtin_amdgcn_mfma_f32_16x16x32_bf16(af[i], bf[j], acc[i][j], 0, 0, 0);
    __builtin_amdgcn_s_setprio(0);
    asm volatile("" ::: "memory");
    __builtin_amdgcn_s_barrier();
    // ---- phase 2: issue next-next tile staging, MFMA second half, counted wait.
    if (t + 2 < KT) stage(t + 2, b);
    asm volatile("" ::: "memory");
    __builtin_amdgcn_s_barrier();
    __builtin_amdgcn_s_setprio(1);
#pragma unroll
    for (int i = 0; i < 8; i++)
#pragma unroll
      for (int j = 2; j < 4; j++)
        acc[i][j] = __builtin_amdgcn_mfma_f32_16x16x32_bf16(af[i], bf[j], acc[i][j], 0, 0, 0);
    __builtin_amdgcn_s_setprio(0);
    if (t + 2 < KT) {
      asm volatile("s_waitcnt vmcnt(4)" ::: "memory");  // tile t+1 landed; t+2 in flight
    } else {
      asm volatile("s_waitcnt vmcnt(0)" ::: "memory");  // tail drain
    }
    __builtin_amdgcn_s_barrier();
  }
}

// NT GEMM core (128-class, 256 threads): C[M,N] += A[M,K] * B^T[N,K] — used by kkkv.
template<int BM, int BN>
__device__ __forceinline__ void gemm_core_nt(
    const unsigned short* __restrict__ A, int lda,
    const unsigned short* __restrict__ B0,
    const unsigned short* __restrict__ B1, int brows0, int ldb,
    int K,
    f32x4 (&acc)[BM / 32][BN / 32],
    unsigned short* As, unsigned short* Bs) {
  constexpr int MT = BM / 32, NT = BN / 32;
  const int tid = threadIdx.x;
  const int lane = tid & 63, wave = tid >> 6;
  const int wm = (wave >> 1) * (BM / 2), wn = (wave & 1) * (BN / 2);
  const int l16 = lane & 15, quad = lane >> 4;
  const int arow = tid >> 2;
  const int akos = (((tid & 3) ^ ((arow >> 1) & 3)) << 3);  // swizzled k-offset
  const int fsw = (l16 >> 1) & 3;                            // frag-read swizzle
#pragma unroll
  for (int i = 0; i < MT; i++)
#pragma unroll
    for (int j = 0; j < NT; j++)
#pragma unroll
      for (int r = 0; r < 4; r++) acc[i][j][r] = 0.f;

  for (int k0 = 0; k0 < K; k0 += 32) {
    __syncthreads();
#pragma unroll
    for (int c = 0; c < BM / 64; c++) {
      const unsigned short* gp = A + (long)(arow + c * 64) * lda + k0 + akos;
      GLD16(gp, As + (c * 256 + wave * 64) * 8);
    }
#pragma unroll
    for (int c = 0; c < BN / 64; c++) {
      int row = arow + c * 64;
      const unsigned short* bp = (row < brows0) ? (B0 + (long)row * ldb)
                                                : (B1 + (long)(row - brows0) * ldb);
      GLD16(bp + k0 + akos, Bs + (c * 256 + wave * 64) * 8);
    }
    __syncthreads();
    bf16x8 af[MT], bfr[NT];
#pragma unroll
    for (int i = 0; i < MT; i++)
      af[i] = *(const bf16x8*)(As + (wm + i * 16 + l16) * 32 + ((quad ^ fsw) * 8));
#pragma unroll
    for (int j = 0; j < NT; j++)
      bfr[j] = *(const bf16x8*)(Bs + (wn + j * 16 + l16) * 32 + ((quad ^ fsw) * 8));
#pragma unroll
    for (int i = 0; i < MT; i++)
#pragma unroll
      for (int j = 0; j < NT; j++)
        acc[i][j] = __builtin_amdgcn_mfma_f32_16x16x32_bf16(af[i], bfr[j], acc[i][j], 0, 0, 0);
  }
}

// ---------------- convert: fp32 -> bf16 ----------------
__global__ __launch_bounds__(256) void k_convert_bf16(const float* __restrict__ in,
                                                      unsigned short* __restrict__ out, long n4) {
  long i = (long)blockIdx.x * 256 + threadIdx.x;
  if (i < n4) {
    float4 v = ((const float4*)in)[i];
    unsigned short o[4] = {f2bf(v.x), f2bf(v.y), f2bf(v.z), f2bf(v.w)};
    ((uint2*)out)[i] = *(uint2*)o;
  }
}

// ---------------- T: tiled batched transpose fp32[R,C] -> bf16[C,R] ----------------
__global__ __launch_bounds__(256) void k_transpose_tiled(const float* __restrict__ in,
                                                         unsigned short* __restrict__ out,
                                                         int R, int C, float scale) {
  __shared__ float t[32][33];
  const float* ib = in + (long)blockIdx.z * R * C;
  unsigned short* ob = out + (long)blockIdx.z * R * C;
  int c0 = blockIdx.x * 32, r0 = blockIdx.y * 32;
  int tx = threadIdx.x & 31, ty = threadIdx.x >> 5;
#pragma unroll
  for (int k = 0; k < 32; k += 8)
    t[ty + k][tx] = ib[(long)(r0 + ty + k) * C + c0 + tx];
  __syncthreads();
#pragma unroll
  for (int k = 0; k < 32; k += 8)
    ob[(long)(c0 + ty + k) * R + r0 + tx] = f2bf(t[tx][ty + k] * scale);
}

// ---------------- K1: qkv GEMM, 256^2 8-wave pipelined core ----------------
__global__ __launch_bounds__(512, 2) void k_gemm_qkv256(const unsigned short* __restrict__ xbf,
                                                        const unsigned short* __restrict__ wqkvT,
                                                        unsigned short* __restrict__ q,
                                                        unsigned short* __restrict__ vT) {
  __shared__ __align__(16) unsigned short smem[36864];  // 64KB staging | 68KB transpose pool
  f32x4 acc[8][4];
  const int L = blockIdx.x;
  const int xcd = L & 7, slot = L >> 3;
  const int rt = xcd * 16 + slot / 6;  // all 6 ct of one rt -> same XCD
  const int ct = slot % 6;
  gemm256_core<24>(xbf + (long)rt * 256 * 768, wqkvT + (long)ct * 256 * 768, 768, acc, smem);

  const int tid = threadIdx.x, lane = tid & 63, wave = tid >> 6;
  const int l16 = lane & 15, quad = lane >> 4;
  const int wr = wave >> 2, wc = wave & 3;
  const int b = rt >> 4;
  const int nbase = (rt & 15) * 256;
  if (ct < 3) {  // pure-q columns -> q[bh][n][d]
#pragma unroll
    for (int i = 0; i < 8; i++)
#pragma unroll
      for (int j = 0; j < 4; j++) {
        int col = ct * 256 + wc * 64 + j * 16 + l16;
        int h = col >> 6, d = col & 63;
#pragma unroll
        for (int r = 0; r < 4; r++) {
          int n = nbase + wr * 128 + i * 16 + quad * 4 + r;
          q[((long)(b * 12 + h) * 4096 + n) * 64 + d] = f2bf(acc[i][j][r]);
        }
      }
  } else {  // pure-v columns: LDS transpose -> vT[bh][d][n]
    unsigned short* pool = smem;  // [col][nloc], stride 136 (2-way banks = free)
    for (int hh = 0; hh < 2; hh++) {
      __syncthreads();
      if (wr == hh) {
#pragma unroll
        for (int i = 0; i < 8; i++)
#pragma unroll
          for (int j = 0; j < 4; j++)
#pragma unroll
            for (int r = 0; r < 4; r++)
              pool[(wc * 64 + j * 16 + l16) * 136 + i * 16 + quad * 4 + r] = f2bf(acc[i][j][r]);
      }
      __syncthreads();
#pragma unroll
      for (int it = 0; it < 8; it++) {
        int chunk = it * 512 + tid;
        int col = chunk >> 4, ng = chunk & 15;
        uint4 val = *(const uint4*)&pool[col * 136 + ng * 8];
        int vcol = (ct - 3) * 256 + col;
        int h = vcol >> 6, d = vcol & 63;
        long n = nbase + hh * 128 + ng * 8;
        *(uint4*)&vT[((long)(b * 12 + h) * 64 + d) * 4096 + n] = val;
      }
    }
  }
}

// ---------------- K3: rf GEMM, full-tile staged, halfnorm folded ----------------
__global__ __launch_bounds__(256) void k_gemm_rf(const unsigned short* __restrict__ q,
                                                 const unsigned short* __restrict__ rmT,
                                                 unsigned short* __restrict__ qnT,
                                                 float* __restrict__ colss) {
  __shared__ __align__(16) unsigned short smem[16384];  // A panels | B panels; pool reuses
  __shared__ float hnp[256];
  __shared__ float css[128];
  unsigned short* Asm = smem;          // 2 panels of 128x32
  unsigned short* Bsm = smem + 8192;   // 2 panels of 128x32
  unsigned short* pool = smem;         // 64x134 transpose buffer (reuses A/B)
  f32x4 acc[4][4];
  const int nt = blockIdx.x, bh = blockIdx.y, h = bh % 12;
  const int tid = threadIdx.x, lane = tid & 63, wave = tid >> 6;
  const int l16 = lane & 15, quad = lane >> 4;
  const int wm = (wave >> 1) * 64, wn = (wave & 1) * 64;
  const int fsw = (l16 >> 1) & 3;
  const unsigned short* Aq = q + ((long)bh * 4096 + nt * 128) * 64;
  const unsigned short* Brm = rmT + (long)h * 8192;

#pragma unroll
  for (int c = 0; c < 4; c++) {  // stage full 128x64 A and B (panelized BK=32, swizzled)
    int chunk = c * 256 + tid;
    int row = chunk >> 3, ko8 = chunk & 7;
    int kc = ko8 >> 2;
    int c2s = (ko8 & 3) ^ ((row >> 1) & 3);
    *(uint4*)(Asm + kc * 4096 + row * 32 + c2s * 8) = *(const uint4*)(Aq + (long)row * 64 + ko8 * 8);
    *(uint4*)(Bsm + kc * 4096 + row * 32 + c2s * 8) = *(const uint4*)(Brm + (long)row * 64 + ko8 * 8);
  }
  for (int i = tid; i < 128; i += 256) css[i] = 0.f;
  __syncthreads();
  {  // halfnorm partials from staged q tile (sum is swizzle-invariant)
    const unsigned short* ap = Asm + (tid & 1) * 4096 + (tid >> 1) * 32;
    float ssum = 0.f;
#pragma unroll
    for (int e = 0; e < 32; e++) { float f = bf2f(ap[e]); ssum += f * f; }
    hnp[tid] = ssum;
  }
#pragma unroll
  for (int i = 0; i < 4; i++)
#pragma unroll
    for (int j = 0; j < 4; j++)
#pragma unroll
      for (int r = 0; r < 4; r++) acc[i][j][r] = 0.f;
#pragma unroll
  for (int kc = 0; kc < 2; kc++) {
    bf16x8 af[4], bfr[4];
#pragma unroll
    for (int i = 0; i < 4; i++)
      af[i] = *(const bf16x8*)(Asm + kc * 4096 + (wm + i * 16 + l16) * 32 + ((quad ^ fsw) * 8));
#pragma unroll
    for (int j = 0; j < 4; j++)
      bfr[j] = *(const bf16x8*)(Bsm + kc * 4096 + (wn + j * 16 + l16) * 32 + ((quad ^ fsw) * 8));
#pragma unroll
    for (int i = 0; i < 4; i++)
#pragma unroll
      for (int j = 0; j < 4; j++)
        acc[i][j] = __builtin_amdgcn_mfma_f32_16x16x32_bf16(af[i], bfr[j], acc[i][j], 0, 0, 0);
  }
  __syncthreads();  // hnp ready; MFMA reads of smem done (pool will reuse)
  float hnv[4][4];
#pragma unroll
  for (int i = 0; i < 4; i++)
#pragma unroll
    for (int r = 0; r < 4; r++) {
      int row = wm + i * 16 + quad * 4 + r;
      hnv[i][r] = 0.0625f * (hnp[2 * row] + hnp[2 * row + 1]);  // 0.5*scale*||q||^2
    }
#pragma unroll
  for (int j = 0; j < 4; j++) {
    int col = wn + j * 16 + l16;
    float cp = 0.f;
#pragma unroll
    for (int i = 0; i < 4; i++)
#pragma unroll
      for (int r = 0; r < 4; r++) {
        float v = __expf(acc[i][j][r] - hnv[i][r]) * 0.08838834764831845f;  // /sqrt(128)
        acc[i][j][r] = v;
        cp += v * v;
      }
    atomicAdd(&css[col], cp);
  }
  __syncthreads();
  for (int i = tid; i < 128; i += 256) atomicAdd(&colss[bh * 128 + i], css[i]);
  // transposed write rf -> qnT[bh][m][n]
  for (int hh = 0; hh < 2; hh++) {
    __syncthreads();
    if ((wave >> 1) == hh) {
#pragma unroll
      for (int i = 0; i < 4; i++)
#pragma unroll
        for (int j = 0; j < 4; j++)
#pragma unroll
          for (int r = 0; r < 4; r++)
            pool[(i * 16 + quad * 4 + r) * 134 + wn + j * 16 + l16] = f2bf(acc[i][j][r]);
    }
    __syncthreads();
#pragma unroll
    for (int c = 0; c < 4; c++) {
      int chunk = tid + c * 256;
      int m = chunk >> 3, nj = (chunk & 7) * 8;
      unsigned short o[8];
#pragma unroll
      for (int e = 0; e < 8; e++) o[e] = pool[(nj + e) * 134 + m];
      *(uint4*)&qnT[((long)bh * 128 + m) * 4096 + nt * 128 + hh * 64 + nj] = *(uint4*)o;
    }
  }
}

// ---------------- K5: kk|kv NT GEMM, rn-scaled, bf16 K-split partials ----------------
__global__ __launch_bounds__(256) void k_gemm_kkkv(const unsigned short* __restrict__ qnT,
                                                   const unsigned short* __restrict__ vT,
                                                   const float* __restrict__ colss,
                                                   unsigned short* __restrict__ kkp) {
  __shared__ __align__(16) unsigned short As[128 * 32], Bs[192 * 32];
  f32x4 acc[4][6];
  const int ks = blockIdx.x, bh = blockIdx.y;
  const unsigned short* A = qnT + (long)bh * 128 * 4096 + ks * 512;
  const unsigned short* B1 = vT + (long)bh * 64 * 4096 + ks * 512;
  gemm_core_nt<128, 192>(A, 4096, A, B1, 128, 4096, 512, acc, As, Bs);
  const int lane = threadIdx.x & 63, wave = threadIdx.x >> 6;
  const int l16 = lane & 15, quad = lane >> 4;
  const int wm = (wave >> 1) * 64, wn = (wave & 1) * 96;
  unsigned short* dst = kkp + ((long)ks * 96 + bh) * 24576;
  float rnr[4][4];
#pragma unroll
  for (int i = 0; i < 4; i++)
#pragma unroll
    for (int r = 0; r < 4; r++)
      rnr[i][r] = rn_of(colss[bh * 128 + wm + i * 16 + quad * 4 + r]);
#pragma unroll
  for (int j = 0; j < 6; j++) {
    int col = wn + j * 16 + l16;
    float rnc = (col < 128) ? rn_of(colss[bh * 128 + col]) : 1.f;
#pragma unroll
    for (int i = 0; i < 4; i++)
#pragma unroll
      for (int r = 0; r < 4; r++) {
        int row = wm + i * 16 + quad * 4 + r;
        dst[row * 192 + col] = f2bf(acc[i][j][r] * rnr[i][r] * rnc);
      }
  }
}

// ---------------- K6: ISTA via MFMA; reduces bf16 partials in fp32 ----------------
__global__ __launch_bounds__(256) void k_ista(const unsigned short* __restrict__ kkp,
                                              const float* __restrict__ colss,
                                              unsigned short* __restrict__ sT) {
  __shared__ __align__(16) unsigned short kks[128 * 144];  // kk bf16
  __shared__ __align__(16) unsigned short ssT[64 * 144];   // s^T bf16 [d][p]
  __shared__ float kvs[128 * 64];                          // kv fp32
  __shared__ float red[128];
  __shared__ float rns[128];
  const int tid = threadIdx.x, lane = tid & 63, wave = tid >> 6;
  const int l16 = lane & 15, quad = lane >> 4;
  const int wm = (wave >> 1) * 64, wn = (wave & 1) * 32;
  const int bh = blockIdx.x;
  const unsigned short* base = kkp + (long)bh * 24576;
  for (int idx = tid; idx < 3072; idx += 256) {  // 128 rows x 24 chunks of 8
    int m = idx / 24, c8 = idx % 24;
    float f[8] = {0.f, 0.f, 0.f, 0.f, 0.f, 0.f, 0.f, 0.f};
#pragma unroll
    for (int ks = 0; ks < 8; ks++) {
      union { uint4 u; unsigned short s[8]; } u;
      u.u = *(const uint4*)(base + (long)ks * 2359296 + m * 192 + c8 * 8);
#pragma unroll
      for (int e = 0; e < 8; e++) f[e] += bf2f(u.s[e]);
    }
    if (c8 < 16) {
#pragma unroll
      for (int e = 0; e < 8; e++) kks[m * 144 + c8 * 8 + e] = f2bf(f[e]);
    } else {
#pragma unroll
      for (int e = 0; e < 8; e++) kvs[m * 64 + (c8 - 16) * 8 + e] = f[e];
    }
  }
  __syncthreads();
  float kv[4][2][4];
#pragma unroll
  for (int i = 0; i < 4; i++)
#pragma unroll
    for (int j = 0; j < 2; j++)
#pragma unroll
      for (int r = 0; r < 4; r++) {
        int m = wm + i * 16 + quad * 4 + r, d = wn + j * 16 + l16;
        kv[i][j][r] = kvs[m * 64 + d];
      }
  if (tid < 128) {  // row L1 norms + rn
    float rs = 0.f;
    const unsigned short* rp = kks + tid * 144;
    for (int p = 0; p < 128; p++) rs += fabsf(bf2f(rp[p]));
    red[tid] = rs;
    rns[tid] = rn_of(colss[bh * 128 + tid]);
  }
  __syncthreads();
  for (int o = 64; o > 0; o >>= 1) {
    if (tid < o) red[tid] = fmaxf(red[tid], red[tid + o]);
    __syncthreads();
  }
  const float L = red[0] + 1.f;
  const float invL = 1.f / L;
  const float lamL = 0.3f * invL;
  float sreg[4][2][4];
#pragma unroll
  for (int i = 0; i < 4; i++)
#pragma unroll
    for (int j = 0; j < 2; j++)
#pragma unroll
      for (int r = 0; r < 4; r++) {
        float z = kv[i][j][r];
        float az = fabsf(z) - 0.3f;
        float s = az > 0.f ? copysignf(az, z) : 0.f;
        sreg[i][j][r] = s;
        ssT[(wn + j * 16 + l16) * 144 + wm + i * 16 + quad * 4 + r] = f2bf(s);
      }
  for (int step = 0; step < 5; step++) {
    __syncthreads();
    f32x4 acc[4][2];
#pragma unroll
    for (int i = 0; i < 4; i++)
#pragma unroll
      for (int j = 0; j < 2; j++)
#pragma unroll
        for (int r = 0; r < 4; r++) acc[i][j][r] = 0.f;
#pragma unroll
    for (int kc = 0; kc < 4; kc++) {
      bf16x8 af[4], bfj[2];
#pragma unroll
      for (int i = 0; i < 4; i++)
        af[i] = *(const bf16x8*)(kks + (wm + i * 16 + l16) * 144 + kc * 32 + quad * 8);
#pragma unroll
      for (int j = 0; j < 2; j++)
        bfj[j] = *(const bf16x8*)(ssT + (wn + j * 16 + l16) * 144 + kc * 32 + quad * 8);
#pragma unroll
      for (int i = 0; i < 4; i++)
#pragma unroll
        for (int j = 0; j < 2; j++)
          acc[i][j] = __builtin_amdgcn_mfma_f32_16x16x32_bf16(af[i], bfj[j], acc[i][j], 0, 0, 0);
    }
    __syncthreads();
#pragma unroll
    for (int i = 0; i < 4; i++)
#pragma unroll
      for (int j = 0; j < 2; j++)
#pragma unroll
        for (int r = 0; r < 4; r++) {
          float z = sreg[i][j][r] - (acc[i][j][r] - kv[i][j][r]) * invL;
          float az = fabsf(z) - lamL;
          float s = az > 0.f ? copysignf(az, z) : 0.f;
          sreg[i][j][r] = s;
          ssT[(wn + j * 16 + l16) * 144 + wm + i * 16 + quad * 4 + r] = f2bf(s);
        }
  }
#pragma unroll
  for (int i = 0; i < 4; i++)
#pragma unroll
    for (int j = 0; j < 2; j++)
#pragma unroll
      for (int r = 0; r < 4; r++) {
        int m = wm + i * 16 + quad * 4 + r, d = wn + j * 16 + l16;
        sT[(long)bh * 8192 + d * 128 + m] = f2bf(sreg[i][j][r] * rns[m]);  // fold rn[m]
      }
}

// ---------------- K7: attn = qn @ s (TN over qnT, gather-staged) ----------------
__global__ __launch_bounds__(256) void k_gemm_attn(const unsigned short* __restrict__ qnT,
                                                   const unsigned short* __restrict__ sT,
                                                   unsigned short* __restrict__ attn) {
  __shared__ __align__(16) unsigned short As2[32 * 128];  // [k][n]
  __shared__ __align__(16) unsigned short Bs[64 * 32];
  f32x4 acc[4][2];
  const int nt = blockIdx.x, bh = blockIdx.y;
  const int b = bh / 12, h = bh % 12;
  const int tid = threadIdx.x, lane = tid & 63, wave = tid >> 6;
  const int l16 = lane & 15, quad = lane >> 4;
  const int wm = (wave >> 1) * 64, wn = (wave & 1) * 32;
  const int fsw = (l16 >> 1) & 3;
#pragma unroll
  for (int i = 0; i < 4; i++)
#pragma unroll
    for (int j = 0; j < 2; j++)
#pragma unroll
      for (int r = 0; r < 4; r++) acc[i][j][r] = 0.f;
  for (int k0 = 0; k0 < 128; k0 += 32) {
    __syncthreads();
#pragma unroll
    for (int c = 0; c < 2; c++) {
      int chunk = tid + c * 256;
      int kr = chunk >> 4, n0 = (chunk & 15) * 8;
      const unsigned short* gp = qnT + ((long)bh * 128 + k0 + kr) * 4096 + nt * 128 + n0;
      GLD16(gp, As2 + (c * 256 + wave * 64) * 8);
    }
    {
      int dd = tid >> 2;
      int ko = (((tid & 3) ^ ((dd >> 1) & 3)) * 8);  // swizzled
      const unsigned short* gp = sT + ((long)bh * 64 + dd) * 128 + k0 + ko;
      GLD16(gp, Bs + wave * 512);
    }
    __syncthreads();
    bf16x8 af[4], bfr[2];
#pragma unroll
    for (int i = 0; i < 4; i++) {
      union { bf16x8 v; unsigned short s[8]; } u;
#pragma unroll
      for (int e = 0; e < 8; e++) u.s[e] = As2[(quad * 8 + e) * 128 + wm + i * 16 + l16];
      af[i] = u.v;
    }
#pragma unroll
    for (int j = 0; j < 2; j++)
      bfr[j] = *(const bf16x8*)&Bs[(wn + j * 16 + l16) * 32 + ((quad ^ fsw) * 8)];
#pragma unroll
    for (int i = 0; i < 4; i++)
#pragma unroll
      for (int j = 0; j < 2; j++)
        acc[i][j] = __builtin_amdgcn_mfma_f32_16x16x32_bf16(af[i], bfr[j], acc[i][j], 0, 0, 0);
  }
#pragma unroll
  for (int i = 0; i < 4; i++)
#pragma unroll
    for (int j = 0; j < 2; j++)
#pragma unroll
      for (int r = 0; r < 4; r++) {
        int n = nt * 128 + wm + i * 16 + quad * 4 + r;
        int dd = wn + j * 16 + l16;
        attn[((long)b * 4096 + n) * 768 + h * 64 + dd] = f2bf(acc[i][j][r]);
      }
}

// ---------------- K8: out = attn @ Wproj + bias, 256^2 8-wave pipelined ----------------
__global__ __launch_bounds__(512, 2) void k_gemm_proj256(const unsigned short* __restrict__ attn,
                                                         const unsigned short* __restrict__ wprojT,
                                                         const float* __restrict__ bias,
                                                         float* __restrict__ out) {
  __shared__ __align__(16) unsigned short smem[32768];
  f32x4 acc[8][4];
  const int L = blockIdx.x;
  const int xcd = L & 7, slot = L >> 3;
  const int rt = xcd * 16 + slot / 3;  // all 3 ct of one rt -> same XCD
  const int ct = slot % 3;
  gemm256_core<24>(attn + (long)rt * 256 * 768, wprojT + (long)ct * 256 * 768, 768, acc, smem);
  const int tid = threadIdx.x, lane = tid & 63, wave = tid >> 6;
  const int l16 = lane & 15, quad = lane >> 4;
  const int wr = wave >> 2, wc = wave & 3;
  const long row0 = (long)rt * 256 + wr * 128;
#pragma unroll
  for (int i = 0; i < 8; i++)
#pragma unroll
    for (int j = 0; j < 4; j++) {
      int col = ct * 256 + wc * 64 + j * 16 + l16;
      float bv = bias[col];
#pragma unroll
      for (int r = 0; r < 4; r++) {
        long row = row0 + i * 16 + quad * 4 + r;
        out[row * 768 + col] = acc[i][j][r] + bv;
      }
    }
}

extern "C" void kernel_launch(void* const* d_in, const int* in_sizes, int n_in,
                              void* d_out, int out_size, void* d_ws, size_t ws_size,
                              hipStream_t stream) {
  const float* x = (const float*)d_in[0];
  const float* Wqkv = (const float*)d_in[1];
  const float* Wproj = (const float*)d_in[2];
  const float* bproj = (const float*)d_in[3];
  const float* rm = (const float*)d_in[4];
  float* out = (float*)d_out;

  size_t o = 0;
  char* wsb = (char*)d_ws;
  auto take = [&](size_t b) { char* p = wsb + o; o += b; return p; };
  unsigned short* wqkvT = (unsigned short*)take(2359296);
  unsigned short* wprojT = (unsigned short*)take(1179648);
  unsigned short* rmT = (unsigned short*)take(196608);
  unsigned short* q = (unsigned short*)take(50331648);    // reused: kkp (37.7MB), then attn
  unsigned short* vT = (unsigned short*)take(50331648);
  float* colss = (float*)take(49152);
  unsigned short* sT = (unsigned short*)take(1572864);
  // total = 106,020,864 B (~101 MB, < proven 110 MB)
  if (ws_size < o) return;

  unsigned short* xbf = (unsigned short*)d_out;  // 48 MB; dead before qnT claims d_out
  unsigned short* qnT = (unsigned short*)d_out;  // 100.66 MB == out bytes; dead before K8
  unsigned short* kkp = q;                       // alias: q dead after rf
  unsigned short* attnbf = q;                    // alias: kkp dead after ista

  hipMemsetAsync(colss, 0, 49152, stream);

  k_convert_bf16<<<24576, 256, 0, stream>>>(x, xbf, 6291456L);
  k_transpose_tiled<<<dim3(48, 24, 1), 256, 0, stream>>>(Wqkv, wqkvT, 768, 1536, 1.0f);
  k_transpose_tiled<<<dim3(24, 24, 1), 256, 0, stream>>>(Wproj, wprojT, 768, 768, 1.0f);
  // fold qs = q * scale^0.5 into rand_matrix (scale^0.5 = 8^-0.5)
  k_transpose_tiled<<<dim3(4, 2, 12), 256, 0, stream>>>(rm, rmT, 64, 128, 0.3535533905932738f);
  k_gemm_qkv256<<<768, 512, 0, stream>>>(xbf, wqkvT, q, vT);
  k_gemm_rf<<<dim3(32, 96), 256, 0, stream>>>(q, rmT, qnT, colss);
  k_gemm_kkkv<<<dim3(8, 96), 256, 0, stream>>>(qnT, vT, colss, kkp);
  k_ista<<<96, 256, 0, stream>>>(kkp, colss, sT);
  k_gemm_attn<<<dim3(32, 96), 256, 0, stream>>>(qnT, sT, attnbf);
  k_gemm_proj256<<<1536 / 4, 512, 0, stream>>>(attnbf, wprojT, bproj, out);
}

// Round 2
// 452.365 us; speedup vs baseline: 1.0442x; 1.0442x over previous
//
#include <hip/hip_runtime.h>

// ---------------------------------------------------------------------------
// VARS_D: fused linear-attention block on gfx950. Round 6.
//  - qkv + proj GEMMs: true m201-style 8-phase schedule. BK=64, 2 K-tiles per
//    iter, 128KB LDS double-buffer. Per phase: {stage half-tile || issue frag
//    ds_reads -> barrier -> lgkmcnt(0) -> 16 MFMA -> barrier}. Reads drain
//    AFTER the barrier (overlap with other waves' MFMA), counted vmcnt(4) at
//    phases 3/7 only. B-frags register-held across phases (minimal LDS reads).
//  - everything else unchanged.
// ---------------------------------------------------------------------------

typedef __attribute__((ext_vector_type(8))) short bf16x8;
typedef __attribute__((ext_vector_type(4))) float f32x4;

#define GLD16(gptr, lptr)                                                              \
  __builtin_amdgcn_global_load_lds((const __attribute__((address_space(1))) void*)(gptr), \
                                   (__attribute__((address_space(3))) void*)(lptr), 16, 0, 0)

__device__ __forceinline__ unsigned short f2bf(float f) {
  union { float f; unsigned int u; } v; v.f = f;
  unsigned int r = v.u + 0x7fffu + ((v.u >> 16) & 1u);   // RNE
  return (unsigned short)(r >> 16);
}
__device__ __forceinline__ float bf2f(unsigned short s) {
  union { unsigned int u; float f; } v; v.u = ((unsigned int)s) << 16;
  return v.f;
}
__device__ __forceinline__ float rn_of(float css) {
  return 1.f / fmaxf(sqrtf(css), 1e-12f);
}

// ---------------------------------------------------------------------------
// 256x256 NT GEMM core, BK=64, 8 waves (2M x 4N), 2x 64KB LDS K-tile buffers,
// 8-phase schedule, counted vmcnt(4). K = ITERS*128.
// LDS row = 64 shorts (8 chunks of 8); chunk pos = c ^ (row&7) (XOR swizzle,
// folded into the global source address; gld_lds dest stays linear).
// Staging WAR proof (per iter, tiles u=2i in buf0 / u+1 in buf1):
//   buf0 B freed after ph1 drain, A after ph2; buf1 B after ph5, A after ph6.
//   ph0:A0(u+1) ph1:A1(u+1) ph2:B0(u+2) ph3:B1(u+2) ph4:A0(u+2) ph5:A1(u+2)
//   ph6:B0(u+3) ph7:B1(u+3)  — every stage is >=2 barriers after last read.
//   vmcnt(4)@ph3 -> prev ph6,7 + ph0,1 landed (all of tile u+1) before ph4.
//   vmcnt(4)@ph7 -> ph2..5 landed (all of tile u+2) before next ph0.
// ---------------------------------------------------------------------------
template<int ITERS>
__device__ __forceinline__ void gemm256_core(
    const unsigned short* __restrict__ A,
    const unsigned short* __restrict__ B,
    int ldk,
    f32x4 (&acc)[8][4],
    unsigned short* smem) {
  const int tid = threadIdx.x;
  const int lane = tid & 63, wave = tid >> 6;
  const int l16 = lane & 15, quad = lane >> 4;
  const int wr = wave >> 2, wc = wave & 3;
  const int rsw = l16 & 7;

#pragma unroll
  for (int i = 0; i < 8; i++)
#pragma unroll
    for (int j = 0; j < 4; j++)
#pragma unroll
      for (int r = 0; r < 4; r++) acc[i][j][r] = 0.f;

  const int srow0 = tid >> 3, sc0 = ((tid & 7) ^ (srow0 & 7)) << 3;
  const int srow1 = (tid + 512) >> 3, sc1 = ((tid & 7) ^ (srow1 & 7)) << 3;
  const int dstw = wave * 512;  // wave-uniform LDS base (shorts)

  auto stageA = [&](int T, int h) {
    const unsigned short* g = A + (long)(h * 128) * ldk + T * 64;
    unsigned short* d = smem + (T & 1) * 32768 + h * 8192 + dstw;
    GLD16(g + (long)srow0 * ldk + sc0, d);
    GLD16(g + (long)srow1 * ldk + sc1, d + 4096);
  };
  auto stageB = [&](int T, int h) {
    const unsigned short* g = B + (long)(h * 128) * ldk + T * 64;
    unsigned short* d = smem + (T & 1) * 32768 + 16384 + h * 8192 + dstw;
    GLD16(g + (long)srow0 * ldk + sc0, d);
    GLD16(g + (long)srow1 * ldk + sc1, d + 4096);
  };

  bf16x8 af[4][2], bn0[2][2], bn1[2][2];

  auto rdA = [&](int b, int mh) {  // own M-half, 8 x ds_read_b128
    const unsigned short* p = smem + b * 32768 + wr * 8192 + (mh * 64 + l16) * 64;
#pragma unroll
    for (int ii = 0; ii < 4; ii++)
#pragma unroll
      for (int ks = 0; ks < 2; ks++)
        af[ii][ks] = *(const bf16x8*)(p + ii * 1024 + (((ks * 4 + quad) ^ rsw) << 3));
  };
  auto rdB = [&](bf16x8 (&bf)[2][2], int b, int nh) {  // own N-quarter, 4 reads
    const unsigned short* p = smem + b * 32768 + 16384 + (wc >> 1) * 8192 +
                              ((wc & 1) * 64 + nh * 32 + l16) * 64;
#pragma unroll
    for (int jj = 0; jj < 2; jj++)
#pragma unroll
      for (int ks = 0; ks < 2; ks++)
        bf[jj][ks] = *(const bf16x8*)(p + jj * 1024 + (((ks * 4 + quad) ^ rsw) << 3));
  };

  auto mma = [&](bf16x8 (&bf)[2][2], int mh, int nh) {
    __builtin_amdgcn_s_setprio(1);
#pragma unroll
    for (int ks = 0; ks < 2; ks++)
#pragma unroll
      for (int ii = 0; ii < 4; ii++)
#pragma unroll
        for (int jj = 0; jj < 2; jj++)
          acc[mh * 4 + ii][nh * 2 + jj] = __builtin_amdgcn_mfma_f32_16x16x32_bf16(
              af[ii][ks], bf[jj][ks], acc[mh * 4 + ii][nh * 2 + jj], 0, 0, 0);
    __builtin_amdgcn_s_setprio(0);
  };

#define FENCE asm volatile("" ::: "memory")
#define DRAIN                                             \
  asm volatile("s_waitcnt lgkmcnt(0)" ::: "memory");      \
  __builtin_amdgcn_sched_barrier(0)

  // prologue: tile0 (all 4 halves) + tile1 B halves; wait tile0 only.
  stageA(0, 0); stageA(0, 1); stageB(0, 0); stageB(0, 1);
  stageB(1, 0); stageB(1, 1);
  asm volatile("s_waitcnt vmcnt(4)" ::: "memory");
  __builtin_amdgcn_s_barrier();

#pragma unroll 1
  for (int i = 0; i < ITERS; i++) {
    const int u = 2 * i;
    const bool more = (i < ITERS - 1);
    // ---- ph0: tile u quadrant (m0,n0)
    stageA(u + 1, 0);
    rdA(0, 0); rdB(bn0, 0, 0);
    FENCE; __builtin_amdgcn_s_barrier(); DRAIN;
    mma(bn0, 0, 0);
    FENCE; __builtin_amdgcn_s_barrier();
    // ---- ph1: (m0,n1)
    stageA(u + 1, 1);
    rdB(bn1, 0, 1);
    FENCE; __builtin_amdgcn_s_barrier(); DRAIN;
    mma(bn1, 0, 1);
    FENCE; __builtin_amdgcn_s_barrier();
    // ---- ph2: (m1,n1)
    if (more) stageB(u + 2, 0);
    rdA(0, 1);
    FENCE; __builtin_amdgcn_s_barrier(); DRAIN;
    mma(bn1, 1, 1);
    FENCE; __builtin_amdgcn_s_barrier();
    // ---- ph3: (m1,n0), counted wait for tile u+1 completeness
    if (more) stageB(u + 2, 1);
    FENCE; __builtin_amdgcn_s_barrier(); DRAIN;
    mma(bn0, 1, 0);
    if (more) { asm volatile("s_waitcnt vmcnt(4)" ::: "memory"); }
    else      { asm volatile("s_waitcnt vmcnt(0)" ::: "memory"); }
    FENCE; __builtin_amdgcn_s_barrier();
    // ---- ph4: tile u+1 quadrant (m0,n0)
    if (more) stageA(u + 2, 0);
    rdA(1, 0); rdB(bn0, 1, 0);
    FENCE; __builtin_amdgcn_s_barrier(); DRAIN;
    mma(bn0, 0, 0);
    FENCE; __builtin_amdgcn_s_barrier();
    // ---- ph5: (m0,n1)
    if (more) stageA(u + 2, 1);
    rdB(bn1, 1, 1);
    FENCE; __builtin_amdgcn_s_barrier(); DRAIN;
    mma(bn1, 0, 1);
    FENCE; __builtin_amdgcn_s_barrier();
    // ---- ph6: (m1,n1)
    if (more) stageB(u + 3, 0);
    rdA(1, 1);
    FENCE; __builtin_amdgcn_s_barrier(); DRAIN;
    mma(bn1, 1, 1);
    FENCE; __builtin_amdgcn_s_barrier();
    // ---- ph7: (m1,n0), counted wait for tile u+2 completeness
    if (more) stageB(u + 3, 1);
    FENCE; __builtin_amdgcn_s_barrier(); DRAIN;
    mma(bn0, 1, 0);
    asm volatile("s_waitcnt vmcnt(4)" ::: "memory");
    FENCE; __builtin_amdgcn_s_barrier();
  }
#undef FENCE
#undef DRAIN
}

// NT GEMM core (128-class, 256 threads): C[M,N] += A[M,K] * B^T[N,K] — used by kkkv.
template<int BM, int BN>
__device__ __forceinline__ void gemm_core_nt(
    const unsigned short* __restrict__ A, int lda,
    const unsigned short* __restrict__ B0,
    const unsigned short* __restrict__ B1, int brows0, int ldb,
    int K,
    f32x4 (&acc)[BM / 32][BN / 32],
    unsigned short* As, unsigned short* Bs) {
  constexpr int MT = BM / 32, NT = BN / 32;
  const int tid = threadIdx.x;
  const int lane = tid & 63, wave = tid >> 6;
  const int wm = (wave >> 1) * (BM / 2), wn = (wave & 1) * (BN / 2);
  const int l16 = lane & 15, quad = lane >> 4;
  const int arow = tid >> 2;
  const int akos = (((tid & 3) ^ ((arow >> 1) & 3)) << 3);  // swizzled k-offset
  const int fsw = (l16 >> 1) & 3;                            // frag-read swizzle
#pragma unroll
  for (int i = 0; i < MT; i++)
#pragma unroll
    for (int j = 0; j < NT; j++)
#pragma unroll
      for (int r = 0; r < 4; r++) acc[i][j][r] = 0.f;

  for (int k0 = 0; k0 < K; k0 += 32) {
    __syncthreads();
#pragma unroll
    for (int c = 0; c < BM / 64; c++) {
      const unsigned short* gp = A + (long)(arow + c * 64) * lda + k0 + akos;
      GLD16(gp, As + (c * 256 + wave * 64) * 8);
    }
#pragma unroll
    for (int c = 0; c < BN / 64; c++) {
      int row = arow + c * 64;
      const unsigned short* bp = (row < brows0) ? (B0 + (long)row * ldb)
                                                : (B1 + (long)(row - brows0) * ldb);
      GLD16(bp + k0 + akos, Bs + (c * 256 + wave * 64) * 8);
    }
    __syncthreads();
    bf16x8 af[MT], bfr[NT];
#pragma unroll
    for (int i = 0; i < MT; i++)
      af[i] = *(const bf16x8*)(As + (wm + i * 16 + l16) * 32 + ((quad ^ fsw) * 8));
#pragma unroll
    for (int j = 0; j < NT; j++)
      bfr[j] = *(const bf16x8*)(Bs + (wn + j * 16 + l16) * 32 + ((quad ^ fsw) * 8));
#pragma unroll
    for (int i = 0; i < MT; i++)
#pragma unroll
      for (int j = 0; j < NT; j++)
        acc[i][j] = __builtin_amdgcn_mfma_f32_16x16x32_bf16(af[i], bfr[j], acc[i][j], 0, 0, 0);
  }
}

// ---------------- convert: fp32 -> bf16 ----------------
__global__ __launch_bounds__(256) void k_convert_bf16(const float* __restrict__ in,
                                                      unsigned short* __restrict__ out, long n4) {
  long i = (long)blockIdx.x * 256 + threadIdx.x;
  if (i < n4) {
    float4 v = ((const float4*)in)[i];
    unsigned short o[4] = {f2bf(v.x), f2bf(v.y), f2bf(v.z), f2bf(v.w)};
    ((uint2*)out)[i] = *(uint2*)o;
  }
}

// ---------------- T: tiled batched transpose fp32[R,C] -> bf16[C,R] ----------------
__global__ __launch_bounds__(256) void k_transpose_tiled(const float* __restrict__ in,
                                                         unsigned short* __restrict__ out,
                                                         int R, int C, float scale) {
  __shared__ float t[32][33];
  const float* ib = in + (long)blockIdx.z * R * C;
  unsigned short* ob = out + (long)blockIdx.z * R * C;
  int c0 = blockIdx.x * 32, r0 = blockIdx.y * 32;
  int tx = threadIdx.x & 31, ty = threadIdx.x >> 5;
#pragma unroll
  for (int k = 0; k < 32; k += 8)
    t[ty + k][tx] = ib[(long)(r0 + ty + k) * C + c0 + tx];
  __syncthreads();
#pragma unroll
  for (int k = 0; k < 32; k += 8)
    ob[(long)(c0 + ty + k) * R + r0 + tx] = f2bf(t[tx][ty + k] * scale);
}

// ---------------- K1: qkv GEMM, 256^2 8-phase core ----------------
__global__ __launch_bounds__(512, 2) void k_gemm_qkv256(const unsigned short* __restrict__ xbf,
                                                        const unsigned short* __restrict__ wqkvT,
                                                        unsigned short* __restrict__ q,
                                                        unsigned short* __restrict__ vT) {
  __shared__ __align__(16) unsigned short smem[65536];  // 128KB staging; pool reuses
  f32x4 acc[8][4];
  const int L = blockIdx.x;
  const int xcd = L & 7, slot = L >> 3;
  const int rt = xcd * 16 + slot / 6;  // all 6 ct of one rt -> same XCD
  const int ct = slot % 6;
  gemm256_core<6>(xbf + (long)rt * 256 * 768, wqkvT + (long)ct * 256 * 768, 768, acc, smem);

  const int tid = threadIdx.x, lane = tid & 63, wave = tid >> 6;
  const int l16 = lane & 15, quad = lane >> 4;
  const int wr = wave >> 2, wc = wave & 3;
  const int b = rt >> 4;
  const int nbase = (rt & 15) * 256;
  if (ct < 3) {  // pure-q columns -> q[bh][n][d]
#pragma unroll
    for (int i = 0; i < 8; i++)
#pragma unroll
      for (int j = 0; j < 4; j++) {
        int col = ct * 256 + wc * 64 + j * 16 + l16;
        int h = col >> 6, d = col & 63;
#pragma unroll
        for (int r = 0; r < 4; r++) {
          int n = nbase + wr * 128 + i * 16 + quad * 4 + r;
          q[((long)(b * 12 + h) * 4096 + n) * 64 + d] = f2bf(acc[i][j][r]);
        }
      }
  } else {  // pure-v columns: LDS transpose -> vT[bh][d][n]
    unsigned short* pool = smem;  // [col][nloc], stride 136 (2-way banks = free)
    for (int hh = 0; hh < 2; hh++) {
      __syncthreads();
      if (wr == hh) {
#pragma unroll
        for (int i = 0; i < 8; i++)
#pragma unroll
          for (int j = 0; j < 4; j++)
#pragma unroll
            for (int r = 0; r < 4; r++)
              pool[(wc * 64 + j * 16 + l16) * 136 + i * 16 + quad * 4 + r] = f2bf(acc[i][j][r]);
      }
      __syncthreads();
#pragma unroll
      for (int it = 0; it < 8; it++) {
        int chunk = it * 512 + tid;
        int col = chunk >> 4, ng = chunk & 15;
        uint4 val = *(const uint4*)&pool[col * 136 + ng * 8];
        int vcol = (ct - 3) * 256 + col;
        int h = vcol >> 6, d = vcol & 63;
        long n = nbase + hh * 128 + ng * 8;
        *(uint4*)&vT[((long)(b * 12 + h) * 64 + d) * 4096 + n] = val;
      }
    }
  }
}

// ---------------- K3: rf GEMM, full-tile staged, halfnorm folded ----------------
__global__ __launch_bounds__(256) void k_gemm_rf(const unsigned short* __restrict__ q,
                                                 const unsigned short* __restrict__ rmT,
                                                 unsigned short* __restrict__ qnT,
                                                 float* __restrict__ colss) {
  __shared__ __align__(16) unsigned short smem[16384];  // A panels | B panels; pool reuses
  __shared__ float hnp[256];
  __shared__ float css[128];
  unsigned short* Asm = smem;          // 2 panels of 128x32
  unsigned short* Bsm = smem + 8192;   // 2 panels of 128x32
  unsigned short* pool = smem;         // 64x134 transpose buffer (reuses A/B)
  f32x4 acc[4][4];
  const int nt = blockIdx.x, bh = blockIdx.y, h = bh % 12;
  const int tid = threadIdx.x, lane = tid & 63, wave = tid >> 6;
  const int l16 = lane & 15, quad = lane >> 4;
  const int wm = (wave >> 1) * 64, wn = (wave & 1) * 64;
  const int fsw = (l16 >> 1) & 3;
  const unsigned short* Aq = q + ((long)bh * 4096 + nt * 128) * 64;
  const unsigned short* Brm = rmT + (long)h * 8192;

#pragma unroll
  for (int c = 0; c < 4; c++) {  // stage full 128x64 A and B (panelized BK=32, swizzled)
    int chunk = c * 256 + tid;
    int row = chunk >> 3, ko8 = chunk & 7;
    int kc = ko8 >> 2;
    int c2s = (ko8 & 3) ^ ((row >> 1) & 3);
    *(uint4*)(Asm + kc * 4096 + row * 32 + c2s * 8) = *(const uint4*)(Aq + (long)row * 64 + ko8 * 8);
    *(uint4*)(Bsm + kc * 4096 + row * 32 + c2s * 8) = *(const uint4*)(Brm + (long)row * 64 + ko8 * 8);
  }
  for (int i = tid; i < 128; i += 256) css[i] = 0.f;
  __syncthreads();
  {  // halfnorm partials from staged q tile (sum is swizzle-invariant)
    const unsigned short* ap = Asm + (tid & 1) * 4096 + (tid >> 1) * 32;
    float ssum = 0.f;
#pragma unroll
    for (int e = 0; e < 32; e++) { float f = bf2f(ap[e]); ssum += f * f; }
    hnp[tid] = ssum;
  }
#pragma unroll
  for (int i = 0; i < 4; i++)
#pragma unroll
    for (int j = 0; j < 4; j++)
#pragma unroll
      for (int r = 0; r < 4; r++) acc[i][j][r] = 0.f;
#pragma unroll
  for (int kc = 0; kc < 2; kc++) {
    bf16x8 af[4], bfr[4];
#pragma unroll
    for (int i = 0; i < 4; i++)
      af[i] = *(const bf16x8*)(Asm + kc * 4096 + (wm + i * 16 + l16) * 32 + ((quad ^ fsw) * 8));
#pragma unroll
    for (int j = 0; j < 4; j++)
      bfr[j] = *(const bf16x8*)(Bsm + kc * 4096 + (wn + j * 16 + l16) * 32 + ((quad ^ fsw) * 8));
#pragma unroll
    for (int i = 0; i < 4; i++)
#pragma unroll
      for (int j = 0; j < 4; j++)
        acc[i][j] = __builtin_amdgcn_mfma_f32_16x16x32_bf16(af[i], bfr[j], acc[i][j], 0, 0, 0);
  }
  __syncthreads();  // hnp ready; MFMA reads of smem done (pool will reuse)
  float hnv[4][4];
#pragma unroll
  for (int i = 0; i < 4; i++)
#pragma unroll
    for (int r = 0; r < 4; r++) {
      int row = wm + i * 16 + quad * 4 + r;
      hnv[i][r] = 0.0625f * (hnp[2 * row] + hnp[2 * row + 1]);  // 0.5*scale*||q||^2
    }
#pragma unroll
  for (int j = 0; j < 4; j++) {
    int col = wn + j * 16 + l16;
    float cp = 0.f;
#pragma unroll
    for (int i = 0; i < 4; i++)
#pragma unroll
      for (int r = 0; r < 4; r++) {
        float v = __expf(acc[i][j][r] - hnv[i][r]) * 0.08838834764831845f;  // /sqrt(128)
        acc[i][j][r] = v;
        cp += v * v;
      }
    atomicAdd(&css[col], cp);
  }
  __syncthreads();
  for (int i = tid; i < 128; i += 256) atomicAdd(&colss[bh * 128 + i], css[i]);
  // transposed write rf -> qnT[bh][m][n]
  for (int hh = 0; hh < 2; hh++) {
    __syncthreads();
    if ((wave >> 1) == hh) {
#pragma unroll
      for (int i = 0; i < 4; i++)
#pragma unroll
        for (int j = 0; j < 4; j++)
#pragma unroll
          for (int r = 0; r < 4; r++)
            pool[(i * 16 + quad * 4 + r) * 134 + wn + j * 16 + l16] = f2bf(acc[i][j][r]);
    }
    __syncthreads();
#pragma unroll
    for (int c = 0; c < 4; c++) {
      int chunk = tid + c * 256;
      int m = chunk >> 3, nj = (chunk & 7) * 8;
      unsigned short o[8];
#pragma unroll
      for (int e = 0; e < 8; e++) o[e] = pool[(nj + e) * 134 + m];
      *(uint4*)&qnT[((long)bh * 128 + m) * 4096 + nt * 128 + hh * 64 + nj] = *(uint4*)o;
    }
  }
}

// ---------------- K5: kk|kv NT GEMM, rn-scaled, bf16 K-split partials ----------------
__global__ __launch_bounds__(256) void k_gemm_kkkv(const unsigned short* __restrict__ qnT,
                                                   const unsigned short* __restrict__ vT,
                                                   const float* __restrict__ colss,
                                                   unsigned short* __restrict__ kkp) {
  __shared__ __align__(16) unsigned short As[128 * 32], Bs[192 * 32];
  f32x4 acc[4][6];
  const int ks = blockIdx.x, bh = blockIdx.y;
  const unsigned short* A = qnT + (long)bh * 128 * 4096 + ks * 512;
  const unsigned short* B1 = vT + (long)bh * 64 * 4096 + ks * 512;
  gemm_core_nt<128, 192>(A, 4096, A, B1, 128, 4096, 512, acc, As, Bs);
  const int lane = threadIdx.x & 63, wave = threadIdx.x >> 6;
  const int l16 = lane & 15, quad = lane >> 4;
  const int wm = (wave >> 1) * 64, wn = (wave & 1) * 96;
  unsigned short* dst = kkp + ((long)ks * 96 + bh) * 24576;
  float rnr[4][4];
#pragma unroll
  for (int i = 0; i < 4; i++)
#pragma unroll
    for (int r = 0; r < 4; r++)
      rnr[i][r] = rn_of(colss[bh * 128 + wm + i * 16 + quad * 4 + r]);
#pragma unroll
  for (int j = 0; j < 6; j++) {
    int col = wn + j * 16 + l16;
    float rnc = (col < 128) ? rn_of(colss[bh * 128 + col]) : 1.f;
#pragma unroll
    for (int i = 0; i < 4; i++)
#pragma unroll
      for (int r = 0; r < 4; r++) {
        int row = wm + i * 16 + quad * 4 + r;
        dst[row * 192 + col] = f2bf(acc[i][j][r] * rnr[i][r] * rnc);
      }
  }
}

// ---------------- K6: ISTA via MFMA; reduces bf16 partials in fp32 ----------------
__global__ __launch_bounds__(256) void k_ista(const unsigned short* __restrict__ kkp,
                                              const float* __restrict__ colss,
                                              unsigned short* __restrict__ sT) {
  __shared__ __align__(16) unsigned short kks[128 * 144];  // kk bf16
  __shared__ __align__(16) unsigned short ssT[64 * 144];   // s^T bf16 [d][p]
  __shared__ float kvs[128 * 64];                          // kv fp32
  __shared__ float red[128];
  __shared__ float rns[128];
  const int tid = threadIdx.x, lane = tid & 63, wave = tid >> 6;
  const int l16 = lane & 15, quad = lane >> 4;
  const int wm = (wave >> 1) * 64, wn = (wave & 1) * 32;
  const int bh = blockIdx.x;
  const unsigned short* base = kkp + (long)bh * 24576;
  for (int idx = tid; idx < 3072; idx += 256) {  // 128 rows x 24 chunks of 8
    int m = idx / 24, c8 = idx % 24;
    float f[8] = {0.f, 0.f, 0.f, 0.f, 0.f, 0.f, 0.f, 0.f};
#pragma unroll
    for (int ks = 0; ks < 8; ks++) {
      union { uint4 u; unsigned short s[8]; } u;
      u.u = *(const uint4*)(base + (long)ks * 2359296 + m * 192 + c8 * 8);
#pragma unroll
      for (int e = 0; e < 8; e++) f[e] += bf2f(u.s[e]);
    }
    if (c8 < 16) {
#pragma unroll
      for (int e = 0; e < 8; e++) kks[m * 144 + c8 * 8 + e] = f2bf(f[e]);
    } else {
#pragma unroll
      for (int e = 0; e < 8; e++) kvs[m * 64 + (c8 - 16) * 8 + e] = f[e];
    }
  }
  __syncthreads();
  float kv[4][2][4];
#pragma unroll
  for (int i = 0; i < 4; i++)
#pragma unroll
    for (int j = 0; j < 2; j++)
#pragma unroll
      for (int r = 0; r < 4; r++) {
        int m = wm + i * 16 + quad * 4 + r, d = wn + j * 16 + l16;
        kv[i][j][r] = kvs[m * 64 + d];
      }
  if (tid < 128) {  // row L1 norms + rn
    float rs = 0.f;
    const unsigned short* rp = kks + tid * 144;
    for (int p = 0; p < 128; p++) rs += fabsf(bf2f(rp[p]));
    red[tid] = rs;
    rns[tid] = rn_of(colss[bh * 128 + tid]);
  }
  __syncthreads();
  for (int o = 64; o > 0; o >>= 1) {
    if (tid < o) red[tid] = fmaxf(red[tid], red[tid + o]);
    __syncthreads();
  }
  const float L = red[0] + 1.f;
  const float invL = 1.f / L;
  const float lamL = 0.3f * invL;
  float sreg[4][2][4];
#pragma unroll
  for (int i = 0; i < 4; i++)
#pragma unroll
    for (int j = 0; j < 2; j++)
#pragma unroll
      for (int r = 0; r < 4; r++) {
        float z = kv[i][j][r];
        float az = fabsf(z) - 0.3f;
        float s = az > 0.f ? copysignf(az, z) : 0.f;
        sreg[i][j][r] = s;
        ssT[(wn + j * 16 + l16) * 144 + wm + i * 16 + quad * 4 + r] = f2bf(s);
      }
  for (int step = 0; step < 5; step++) {
    __syncthreads();
    f32x4 acc[4][2];
#pragma unroll
    for (int i = 0; i < 4; i++)
#pragma unroll
      for (int j = 0; j < 2; j++)
#pragma unroll
        for (int r = 0; r < 4; r++) acc[i][j][r] = 0.f;
#pragma unroll
    for (int kc = 0; kc < 4; kc++) {
      bf16x8 af[4], bfj[2];
#pragma unroll
      for (int i = 0; i < 4; i++)
        af[i] = *(const bf16x8*)(kks + (wm + i * 16 + l16) * 144 + kc * 32 + quad * 8);
#pragma unroll
      for (int j = 0; j < 2; j++)
        bfj[j] = *(const bf16x8*)(ssT + (wn + j * 16 + l16) * 144 + kc * 32 + quad * 8);
#pragma unroll
      for (int i = 0; i < 4; i++)
#pragma unroll
        for (int j = 0; j < 2; j++)
          acc[i][j] = __builtin_amdgcn_mfma_f32_16x16x32_bf16(af[i], bfj[j], acc[i][j], 0, 0, 0);
    }
    __syncthreads();
#pragma unroll
    for (int i = 0; i < 4; i++)
#pragma unroll
      for (int j = 0; j < 2; j++)
#pragma unroll
        for (int r = 0; r < 4; r++) {
          float z = sreg[i][j][r] - (acc[i][j][r] - kv[i][j][r]) * invL;
          float az = fabsf(z) - lamL;
          float s = az > 0.f ? copysignf(az, z) : 0.f;
          sreg[i][j][r] = s;
          ssT[(wn + j * 16 + l16) * 144 + wm + i * 16 + quad * 4 + r] = f2bf(s);
        }
  }
#pragma unroll
  for (int i = 0; i < 4; i++)
#pragma unroll
    for (int j = 0; j < 2; j++)
#pragma unroll
      for (int r = 0; r < 4; r++) {
        int m = wm + i * 16 + quad * 4 + r, d = wn + j * 16 + l16;
        sT[(long)bh * 8192 + d * 128 + m] = f2bf(sreg[i][j][r] * rns[m]);  // fold rn[m]
      }
}

// ---------------- K7: attn = qn @ s (TN over qnT, gather-staged) ----------------
__global__ __launch_bounds__(256) void k_gemm_attn(const unsigned short* __restrict__ qnT,
                                                   const unsigned short* __restrict__ sT,
                                                   unsigned short* __restrict__ attn) {
  __shared__ __align__(16) unsigned short As2[32 * 128];  // [k][n]
  __shared__ __align__(16) unsigned short Bs[64 * 32];
  f32x4 acc[4][2];
  const int nt = blockIdx.x, bh = blockIdx.y;
  const int b = bh / 12, h = bh % 12;
  const int tid = threadIdx.x, lane = tid & 63, wave = tid >> 6;
  const int l16 = lane & 15, quad = lane >> 4;
  const int wm = (wave >> 1) * 64, wn = (wave & 1) * 32;
  const int fsw = (l16 >> 1) & 3;
#pragma unroll
  for (int i = 0; i < 4; i++)
#pragma unroll
    for (int j = 0; j < 2; j++)
#pragma unroll
      for (int r = 0; r < 4; r++) acc[i][j][r] = 0.f;
  for (int k0 = 0; k0 < 128; k0 += 32) {
    __syncthreads();
#pragma unroll
    for (int c = 0; c < 2; c++) {
      int chunk = tid + c * 256;
      int kr = chunk >> 4, n0 = (chunk & 15) * 8;
      const unsigned short* gp = qnT + ((long)bh * 128 + k0 + kr) * 4096 + nt * 128 + n0;
      GLD16(gp, As2 + (c * 256 + wave * 64) * 8);
    }
    {
      int dd = tid >> 2;
      int ko = (((tid & 3) ^ ((dd >> 1) & 3)) * 8);  // swizzled
      const unsigned short* gp = sT + ((long)bh * 64 + dd) * 128 + k0 + ko;
      GLD16(gp, Bs + wave * 512);
    }
    __syncthreads();
    bf16x8 af[4], bfr[2];
#pragma unroll
    for (int i = 0; i < 4; i++) {
      union { bf16x8 v; unsigned short s[8]; } u;
#pragma unroll
      for (int e = 0; e < 8; e++) u.s[e] = As2[(quad * 8 + e) * 128 + wm + i * 16 + l16];
      af[i] = u.v;
    }
#pragma unroll
    for (int j = 0; j < 2; j++)
      bfr[j] = *(const bf16x8*)&Bs[(wn + j * 16 + l16) * 32 + ((quad ^ fsw) * 8)];
#pragma unroll
    for (int i = 0; i < 4; i++)
#pragma unroll
      for (int j = 0; j < 2; j++)
        acc[i][j] = __builtin_amdgcn_mfma_f32_16x16x32_bf16(af[i], bfr[j], acc[i][j], 0, 0, 0);
  }
#pragma unroll
  for (int i = 0; i < 4; i++)
#pragma unroll
    for (int j = 0; j < 2; j++)
#pragma unroll
      for (int r = 0; r < 4; r++) {
        int n = nt * 128 + wm + i * 16 + quad * 4 + r;
        int dd = wn + j * 16 + l16;
        attn[((long)b * 4096 + n) * 768 + h * 64 + dd] = f2bf(acc[i][j][r]);
      }
}

// ---------------- K8: out = attn @ Wproj + bias, 256^2 8-phase core ----------------
__global__ __launch_bounds__(512, 2) void k_gemm_proj256(const unsigned short* __restrict__ attn,
                                                         const unsigned short* __restrict__ wprojT,
                                                         const float* __restrict__ bias,
                                                         float* __restrict__ out) {
  __shared__ __align__(16) unsigned short smem[65536];
  f32x4 acc[8][4];
  const int L = blockIdx.x;
  const int xcd = L & 7, slot = L >> 3;
  const int rt = xcd * 16 + slot / 3;  // all 3 ct of one rt -> same XCD
  const int ct = slot % 3;
  gemm256_core<6>(attn + (long)rt * 256 * 768, wprojT + (long)ct * 256 * 768, 768, acc, smem);
  const int tid = threadIdx.x, lane = tid & 63, wave = tid >> 6;
  const int l16 = lane & 15, quad = lane >> 4;
  const int wr = wave >> 2, wc = wave & 3;
  const long row0 = (long)rt * 256 + wr * 128;
#pragma unroll
  for (int i = 0; i < 8; i++)
#pragma unroll
    for (int j = 0; j < 4; j++) {
      int col = ct * 256 + wc * 64 + j * 16 + l16;
      float bv = bias[col];
#pragma unroll
      for (int r = 0; r < 4; r++) {
        long row = row0 + i * 16 + quad * 4 + r;
        out[row * 768 + col] = acc[i][j][r] + bv;
      }
    }
}

extern "C" void kernel_launch(void* const* d_in, const int* in_sizes, int n_in,
                              void* d_out, int out_size, void* d_ws, size_t ws_size,
                              hipStream_t stream) {
  const float* x = (const float*)d_in[0];
  const float* Wqkv = (const float*)d_in[1];
  const float* Wproj = (const float*)d_in[2];
  const float* bproj = (const float*)d_in[3];
  const float* rm = (const float*)d_in[4];
  float* out = (float*)d_out;

  size_t o = 0;
  char* wsb = (char*)d_ws;
  auto take = [&](size_t b) { char* p = wsb + o; o += b; return p; };
  unsigned short* wqkvT = (unsigned short*)take(2359296);
  unsigned short* wprojT = (unsigned short*)take(1179648);
  unsigned short* rmT = (unsigned short*)take(196608);
  unsigned short* q = (unsigned short*)take(50331648);    // reused: kkp (37.7MB), then attn
  unsigned short* vT = (unsigned short*)take(50331648);
  float* colss = (float*)take(49152);
  unsigned short* sT = (unsigned short*)take(1572864);
  // total = 106,020,864 B (~101 MB, < proven 110 MB)
  if (ws_size < o) return;

  unsigned short* xbf = (unsigned short*)d_out;  // 48 MB; dead before qnT claims d_out
  unsigned short* qnT = (unsigned short*)d_out;  // 100.66 MB == out bytes; dead before K8
  unsigned short* kkp = q;                       // alias: q dead after rf
  unsigned short* attnbf = q;                    // alias: kkp dead after ista

  hipMemsetAsync(colss, 0, 49152, stream);

  k_convert_bf16<<<24576, 256, 0, stream>>>(x, xbf, 6291456L);
  k_transpose_tiled<<<dim3(48, 24, 1), 256, 0, stream>>>(Wqkv, wqkvT, 768, 1536, 1.0f);
  k_transpose_tiled<<<dim3(24, 24, 1), 256, 0, stream>>>(Wproj, wprojT, 768, 768, 1.0f);
  // fold qs = q * scale^0.5 into rand_matrix (scale^0.5 = 8^-0.5)
  k_transpose_tiled<<<dim3(4, 2, 12), 256, 0, stream>>>(rm, rmT, 64, 128, 0.3535533905932738f);
  k_gemm_qkv256<<<768, 512, 0, stream>>>(xbf, wqkvT, q, vT);
  k_gemm_rf<<<dim3(32, 96), 256, 0, stream>>>(q, rmT, qnT, colss);
  k_gemm_kkkv<<<dim3(8, 96), 256, 0, stream>>>(qnT, vT, colss, kkp);
  k_ista<<<96, 256, 0, stream>>>(kkp, colss, sT);
  k_gemm_attn<<<dim3(32, 96), 256, 0, stream>>>(qnT, sT, attnbf);
  k_gemm_proj256<<<384, 512, 0, stream>>>(attnbf, wprojT, bproj, out);
}